// Round 5
// baseline (140.870 us; speedup 1.0000x reference)
//
#include <hip/hip_runtime.h>

#define LDIM 1024
#define NSHIFT 10

// One wave (64 lanes) per output row (b, i).
// Phase 1: wave-uniform computation of the 21-bit band word
//          (bit 10+d, d in [-10,10] => out[b,i,i+d]).
// Phase 2: write the full 4 KB row as 4 coalesced 1 KB int4 stores;
//          band membership folded in via the bit word (no loads in loop).
__global__ __launch_bounds__(256) void chunk_mask_full(
    const int* __restrict__ mask, int4* __restrict__ outv)
{
    const int wave = (blockIdx.x << 2) | (threadIdx.x >> 6);  // row id: (b<<10)|i
    const int lane = threadIdx.x & 63;
    const int b = wave >> 10;
    const int i = wave & (LDIM - 1);
    const int* __restrict__ mrow = mask + (b << 10);

    // ---- band word: 20 independent broadcast loads, two prefix-ANDs ----
    unsigned int bits = 1u << NSHIFT;   // diagonal
    int prod = 1;
#pragma unroll
    for (int d = 1; d <= NSHIFT; ++d) {             // j = i-d: need mrow[i-d+1..i] all 0
        const int k = i - d + 1;
        const int mv = (k >= 1) ? mrow[k] : 1;      // j<0 -> force 0
        prod &= (mv == 0) ? 1 : 0;
        bits |= (unsigned int)prod << (NSHIFT - d);
    }
    prod = 1;
#pragma unroll
    for (int d = 1; d <= NSHIFT; ++d) {             // j = i+d: need mrow[i+1..i+d] all 0
        const int k = i + d;
        const int mv = (k < LDIM) ? mrow[k] : 1;    // j>=L -> force 0
        prod &= (mv == 0) ? 1 : 0;
        bits |= (unsigned int)prod << (NSHIFT + d);
    }

    // ---- write the row: 4 iterations x 64 lanes x int4 = 1024 ints ----
    int4* __restrict__ rowv = outv + ((size_t)wave << 8);   // 256 int4 per row
#pragma unroll
    for (int it = 0; it < 4; ++it) {
        const int cchunk = it << 8;                 // first column of this 1KB chunk
        int4 v = make_int4(0, 0, 0, 0);
        // wave-uniform: does chunk [cchunk, cchunk+255] touch the band?
        if (cchunk <= i + NSHIFT && cchunk + 255 >= i - NSHIFT) {
            const int base = cchunk + (lane << 2) - i + NSHIFT;  // bit idx for elem 0
            v.x = ((unsigned)(base    ) <= 2u * NSHIFT) ? (int)((bits >> (base    )) & 1u) : 0;
            v.y = ((unsigned)(base + 1) <= 2u * NSHIFT) ? (int)((bits >> (base + 1)) & 1u) : 0;
            v.z = ((unsigned)(base + 2) <= 2u * NSHIFT) ? (int)((bits >> (base + 2)) & 1u) : 0;
            v.w = ((unsigned)(base + 3) <= 2u * NSHIFT) ? (int)((bits >> (base + 3)) & 1u) : 0;
        }
        rowv[(it << 6) + lane] = v;
    }
}

extern "C" void kernel_launch(void* const* d_in, const int* in_sizes, int n_in,
                              void* d_out, int out_size, void* d_ws, size_t ws_size,
                              hipStream_t stream) {
    const int* mask = (const int*)d_in[0];
    int4* outv = (int4*)d_out;

    const int B = in_sizes[0] / LDIM;   // 32
    const int n_rows = B * LDIM;        // 32768 rows = 32768 waves

    // 4 waves (rows) per 256-thread block -> 8192 blocks, single launch.
    chunk_mask_full<<<n_rows / 4, 256, 0, stream>>>(mask, outv);
}

// Round 7
// 140.368 us; speedup vs baseline: 1.0036x; 1.0036x over previous
//
#include <hip/hip_runtime.h>

#define LDIM 1024
#define NSHIFT 10
#define RPW 8   // rows per wave (1024 % 8 == 0 -> no batch crossing)

typedef int v4i __attribute__((ext_vector_type(4)));

// One wave per 8 consecutive output rows. Per row: wave-uniform 21-bit band
// word (20 L1-hot broadcast loads, two prefix-ANDs), then 4 coalesced 1 KB
// nontemporal stores. 4096 waves total, each streaming 32 KB.
__global__ __launch_bounds__(256) void chunk_mask_full(
    const int* __restrict__ mask, v4i* __restrict__ outv)
{
    const int wid  = (blockIdx.x << 2) | (threadIdx.x >> 6);
    const int lane = threadIdx.x & 63;
    const int row0 = wid * RPW;                   // (b<<10) | i0
    const int* __restrict__ mrow = mask + ((row0 >> 10) << 10);

    for (int r = 0; r < RPW; ++r) {
        const int row = row0 + r;
        const int i = row & (LDIM - 1);

        // ---- band word: bit (10+d) = out[b,i,i+d], d in [-10,10] ----
        unsigned int bits = 1u << NSHIFT;
        int prod = 1;
#pragma unroll
        for (int d = 1; d <= NSHIFT; ++d) {       // j = i-d: mrow[i-d+1..i] all 0
            const int k = i - d + 1;
            const int mv = (k >= 1) ? mrow[k] : 1;
            prod &= (mv == 0) ? 1 : 0;
            bits |= (unsigned int)prod << (NSHIFT - d);
        }
        prod = 1;
#pragma unroll
        for (int d = 1; d <= NSHIFT; ++d) {       // j = i+d: mrow[i+1..i+d] all 0
            const int k = i + d;
            const int mv = (k < LDIM) ? mrow[k] : 1;
            prod &= (mv == 0) ? 1 : 0;
            bits |= (unsigned int)prod << (NSHIFT + d);
        }

        // ---- 4 x 1 KB coalesced nontemporal stores ----
        v4i* __restrict__ rowv = outv + ((size_t)row << 8);
#pragma unroll
        for (int it = 0; it < 4; ++it) {
            const int cchunk = it << 8;
            v4i v = (v4i){0, 0, 0, 0};
            if (cchunk <= i + NSHIFT && cchunk + 255 >= i - NSHIFT) {  // wave-uniform
                const int base = cchunk + (lane << 2) - i + NSHIFT;
                v.x = ((unsigned)(base    ) <= 2u * NSHIFT) ? (int)((bits >> (base    )) & 1u) : 0;
                v.y = ((unsigned)(base + 1) <= 2u * NSHIFT) ? (int)((bits >> (base + 1)) & 1u) : 0;
                v.z = ((unsigned)(base + 2) <= 2u * NSHIFT) ? (int)((bits >> (base + 2)) & 1u) : 0;
                v.w = ((unsigned)(base + 3) <= 2u * NSHIFT) ? (int)((bits >> (base + 3)) & 1u) : 0;
            }
            __builtin_nontemporal_store(v, &rowv[(it << 6) + lane]);
        }
    }
}

extern "C" void kernel_launch(void* const* d_in, const int* in_sizes, int n_in,
                              void* d_out, int out_size, void* d_ws, size_t ws_size,
                              hipStream_t stream) {
    const int* mask = (const int*)d_in[0];
    v4i* outv = (v4i*)d_out;

    const int B = in_sizes[0] / LDIM;             // 32
    const int n_rows = B * LDIM;                  // 32768
    const int n_blocks = n_rows / (4 * RPW);      // 1024 blocks (4 waves each)

    chunk_mask_full<<<n_blocks, 256, 0, stream>>>(mask, outv);
}